// Round 6
// baseline (270.143 us; speedup 1.0000x reference)
//
#include <hip/hip_runtime.h>
#include <cstdint>
#include <cstddef>

typedef unsigned short u16;
typedef unsigned int   u32;
typedef __attribute__((ext_vector_type(8))) short bf16x8;
typedef __attribute__((ext_vector_type(4))) float f32x4;

#define D_IN  256
#define D_H   128
#define D_OUT 64

__device__ __forceinline__ float bf2f(u16 u){
  union { u32 i; float f; } v; v.i = ((u32)u) << 16; return v.f;
}
__device__ __forceinline__ u16 f2bf(float f){
  union { float f; u32 i; } v; v.f = f;
  u32 r = (v.i + 0x7fffu + ((v.i >> 16) & 1u)) >> 16;
  return (u16)r;
}

// ---------------- weight prep + deg zero (fused) ----------------
__global__ void k_wprep(const float* __restrict__ W0, const float* __restrict__ W1,
                        u16* __restrict__ W0t, u16* __restrict__ W1t,
                        int* __restrict__ deg, int n_t){
  int i = blockIdx.x * 256 + threadIdx.x;
  if (i < 128 * 256){
    int n = i >> 8, k = i & 255;
    W0t[i] = f2bf(W0[(size_t)k * 128 + n]);
  } else if (i < 128 * 256 + 64 * 128){
    int j = i - 128 * 256;
    int n = j >> 7, k = j & 127;
    W1t[j] = f2bf(W1[(size_t)k * 64 + n]);
  } else if (i - (128 * 256 + 64 * 128) < n_t){
    deg[i - (128 * 256 + 64 * 128)] = 0;
  }
}

// ---------------- offsets: direct deg-sum (replaces bsum+off pair) ----------------
__global__ __launch_bounds__(256) void k_off(const int* __restrict__ deg, int N,
                                             int* __restrict__ off, int* __restrict__ cursor,
                                             float* __restrict__ dinv){
  __shared__ int s[256];
  __shared__ int sbase[256];
  const int tid = threadIdx.x;
  const int bid = blockIdx.x;
  const int i   = bid * 256 + tid;
  // block base = sum of deg[0 .. bid*256) read directly (coalesced strided)
  int acc = 0;
  const int lim = bid * 256;
  for (int j = tid; j < lim; j += 256) acc += deg[j];
  sbase[tid] = acc;
  int v = (i < N) ? deg[i] : 0;
  s[tid] = v;
  __syncthreads();
  for (int o = 128; o > 0; o >>= 1){
    if (tid < o) sbase[tid] += sbase[tid + o];
    __syncthreads();
  }
  for (int o = 1; o < 256; o <<= 1){
    int tv = (tid >= o) ? s[tid - o] : 0;
    __syncthreads();
    s[tid] += tv;
    __syncthreads();
  }
  if (i < N){
    int excl = s[tid] - v + sbase[0];
    off[i] = excl;
    cursor[i] = excl;
    dinv[i] = rsqrtf((float)v + 1.0f);
  }
}

__global__ void k_fill(const int* __restrict__ src, const int* __restrict__ dst,
                       int E, int* __restrict__ cursor, int* __restrict__ csr){
  int e = blockIdx.x * 256 + threadIdx.x;
  if (e < E){
    int d = dst[e];
    int p = atomicAdd(&cursor[d], 1);
    csr[p] = src[e];
  }
}

// ---------------- K2: GEMM1 (persistent-B LDS, forced full-row A prefetch)
//                      with deg-count fused into the prologue ----------------
// sched_barrier(0) pins all 16 A-loads above the MFMA loop (R5's VGPR=56
// proved the compiler sank them otherwise). deg atomics are fire-and-forget,
// issued while staging B / waiting on A — a free launch removal.
__global__ __launch_bounds__(512, 4) void k_g1deg(
    const float* __restrict__ Xs, const float* __restrict__ Xt,
    const u16* __restrict__ W0t, int M, int n_s,
    const int* __restrict__ dst, int E, int* __restrict__ deg,
    u16* __restrict__ out)
{
  __shared__ u16 Bs[128 * 256];   // 64 KB; cell (n,kbyte) at n*512 + (kbyte ^ ((n&15)<<4))
  const int t    = threadIdx.x;
  const int wave = t >> 6, lane = t & 63;
  const int lm   = lane & 15, quad = lane >> 4;
  const int gw   = blockIdx.x * 8 + wave;   // global wave id
  const int row  = gw * 16 + lm;            // A row this lane reads

  int cr = (row < M) ? row : 0;
  const float* pa = ((cr < n_s) ? (Xs + (size_t)cr * D_IN)
                                : (Xt + (size_t)(cr - n_s) * D_IN)) + quad * 8;

  float4 a[8][2];
  // issue A k-steps 0..1 first
  a[0][0] = *(const float4*)(pa +  0); a[0][1] = *(const float4*)(pa +  4);
  a[1][0] = *(const float4*)(pa + 32); a[1][1] = *(const float4*)(pa + 36);

  // fused deg count: this block's slice of edges (<=2 per thread here)
  {
    const int stride = (int)gridDim.x * 512;
    int e = blockIdx.x * 512 + t;
    if (e < E) atomicAdd(&deg[dst[e]], 1);
    e += stride;
    if (e < E) atomicAdd(&deg[dst[e]], 1);
    for (e += stride; e < E; e += stride) atomicAdd(&deg[dst[e]], 1);
  }

  // stage B once: thread t -> n = t>>2 (0..127), 128 B chunk c = t&3
  {
    const int n = t >> 2;
    const int c = t & 3;
    const u16* wsrc = W0t + (size_t)n * 256 + c * 64;
    char* brow = (char*)Bs + n * 512;
    const int sw = (n & 15) << 4;
    #pragma unroll
    for (int j = 0; j < 8; j++){
      int off = (c * 128 + j * 16) ^ sw;
      *(int4*)(brow + off) = *(const int4*)(wsrc + j * 8);
    }
  }

  // issue remaining 6 K-steps
  #pragma unroll
  for (int s = 2; s < 8; s++){
    a[s][0] = *(const float4*)(pa + s * 32);
    a[s][1] = *(const float4*)(pa + s * 32 + 4);
  }
  // pin: nothing above may sink below (keeps all 16 loads in flight)
  __builtin_amdgcn_sched_barrier(0);

  f32x4 acc[8];
  const f32x4 z = {0.f, 0.f, 0.f, 0.f};
  #pragma unroll
  for (int nf = 0; nf < 8; nf++) acc[nf] = z;

  __syncthreads();

  const char* bb = (const char*)Bs + lm * 512;  // B row base for this lane's lm
  const int lmx = lm << 4;

  #pragma unroll
  for (int kk = 0; kk < 8; kk++){
    bf16x8 af;
    {
      const float* fa = (const float*)&a[kk][0];
      u16 tmp[8];
      #pragma unroll
      for (int q = 0; q < 8; q++) tmp[q] = f2bf(fa[q]);
      af = *(const bf16x8*)tmp;
    }
    const int koff = (kk * 64 + quad * 16) ^ lmx;   // swizzled in-row byte offset
    #pragma unroll
    for (int nf = 0; nf < 8; nf++){
      bf16x8 bf = *(const bf16x8*)(bb + nf * 8192 + koff);
      acc[nf] = __builtin_amdgcn_mfma_f32_16x16x32_bf16(af, bf, acc[nf], 0, 0, 0);
    }
  }

  {
    int rbase = gw * 16 + quad * 4;
    #pragma unroll
    for (int rr = 0; rr < 4; rr++){
      int m = rbase + rr;
      if (m >= M) continue;
      u16* op = out + (size_t)m * D_H + lm;
      #pragma unroll
      for (int nf = 0; nf < 8; nf++)
        op[nf * 16] = f2bf(acc[nf][rr]);
    }
  }
}

// ---------------- aggregation body (one wave per dst node) ----------------
__device__ __forceinline__ void aggf_body(
    const int* __restrict__ off, const int* __restrict__ deg,
    const int* __restrict__ csr, const float* __restrict__ dinv,
    u16* __restrict__ h1, int n_s, int n_t, int w, int lane)
{
  if (w >= n_t) return;
  const int g = lane >> 4;
  const int c = lane & 15;
  int start = off[w];
  int n     = deg[w];

  float r[8], p[8];
  #pragma unroll
  for (int q = 0; q < 8; q++){ r[q] = 0.f; p[q] = 0.f; }

  int i = 0;
  for (; i + 8 <= n; i += 8){
    int sa = csr[start + i + g];
    int sb = csr[start + i + 4 + g];
    int4 da = *(const int4*)(h1 + (size_t)sa * D_H + c * 8);
    int4 db = *(const int4*)(h1 + (size_t)sb * D_H + c * 8);
    const u16* ha = (const u16*)&da;
    const u16* hb = (const u16*)&db;
    #pragma unroll
    for (int q = 0; q < 8; q++){
      float va = bf2f(ha[q]), vb = bf2f(hb[q]);
      r[q] += va + vb;
      p[q] += fmaxf(va, 0.f) + fmaxf(vb, 0.f);
    }
  }
  for (; i < n; i += 4){
    if (i + g < n){
      int sa = csr[start + i + g];
      int4 da = *(const int4*)(h1 + (size_t)sa * D_H + c * 8);
      const u16* ha = (const u16*)&da;
      #pragma unroll
      for (int q = 0; q < 8; q++){
        float va = bf2f(ha[q]);
        r[q] += va;
        p[q] += fmaxf(va, 0.f);
      }
    }
  }

  #pragma unroll
  for (int q = 0; q < 8; q++){
    r[q] += __shfl_xor(r[q], 16, 64);
    r[q] += __shfl_xor(r[q], 32, 64);
    p[q] += __shfl_xor(p[q], 16, 64);
    p[q] += __shfl_xor(p[q], 32, 64);
  }

  if (g == 0){
    float di  = dinv[w];
    float di2 = di * di;
    u16* selfp = h1 + (size_t)(n_s + w) * D_H + c * 8;
    int4 hs = *(const int4*)selfp;
    const u16* hh = (const u16*)&hs;
    u16 ob[8];
    #pragma unroll
    for (int q = 0; q < 8; q++){
      float zq = fmaxf(di * r[q] + di2 * bf2f(hh[q]), 0.f);
      float uq = di * p[q] + di2 * zq;
      ob[q] = f2bf(uq);
    }
    *(int4*)selfp = *(int4*)ob;
  }
}

// ---------------- gemm2 body (B=16 KB LDS, full-K A prefetch), row-ranged ----------------
__device__ __forceinline__ bf16x8 relu_bf(int4 v, bool relu){
  const u16* s = (const u16*)&v;
  u16 tmp[8];
  #pragma unroll
  for (int q = 0; q < 8; q++){
    u16 x = s[q];
    tmp[q] = (relu && (x & 0x8000u)) ? (u16)0 : x;
  }
  return *(const bf16x8*)tmp;
}

__device__ __forceinline__ void gemm2_body(
    const u16* __restrict__ h1, const u16* __restrict__ W1t,
    int gb, int base, int rowLim, int n_s, float* __restrict__ out,
    u16* Bs)
{
  const int t    = threadIdx.x;
  const int wave = t >> 6, lane = t & 63;
  const int lm   = lane & 15, quad = lane >> 4;
  const int gw   = gb * 8 + wave;
  const int row  = base + gw * 16 + lm;

  int cr = (row < rowLim) ? row : base;
  const bool relu = (cr < n_s);
  const u16* pa = h1 + (size_t)cr * D_H + quad * 8;

  // full-K A prefetch: 4 int4, zero loads in the loop
  int4 a[4];
  a[0] = *(const int4*)(pa);
  a[1] = *(const int4*)(pa + 32);

  // stage B once: thread t -> n = t>>3 (0..63), 32 B chunk c = t&7
  {
    const int n = t >> 3;
    const int c = t & 7;
    const u16* wsrc = W1t + (size_t)n * 128 + c * 16;
    char* brow = (char*)Bs + n * 256;
    const int sw = (n & 15) << 4;
    #pragma unroll
    for (int j = 0; j < 2; j++){
      int off = (c * 32 + j * 16) ^ sw;
      *(int4*)(brow + off) = *(const int4*)(wsrc + j * 8);
    }
  }
  a[2] = *(const int4*)(pa + 64);
  a[3] = *(const int4*)(pa + 96);
  __builtin_amdgcn_sched_barrier(0);

  f32x4 acc[4];
  const f32x4 z = {0.f, 0.f, 0.f, 0.f};
  #pragma unroll
  for (int nf = 0; nf < 4; nf++) acc[nf] = z;

  __syncthreads();

  const char* bb = (const char*)Bs + lm * 256;
  const int lmx = lm << 4;

  #pragma unroll
  for (int kk = 0; kk < 4; kk++){
    bf16x8 af = relu_bf(a[kk], relu);
    const int koff = (kk * 64 + quad * 16) ^ lmx;
    #pragma unroll
    for (int nf = 0; nf < 4; nf++){
      bf16x8 bf = *(const bf16x8*)(bb + nf * 4096 + koff);
      acc[nf] = __builtin_amdgcn_mfma_f32_16x16x32_bf16(af, bf, acc[nf], 0, 0, 0);
    }
  }

  {
    int rbase = base + gw * 16 + quad * 4;
    #pragma unroll
    for (int rr = 0; rr < 4; rr++){
      int m = rbase + rr;
      if (m >= rowLim) continue;
      float* op = out + (size_t)m * D_OUT + lm;
      #pragma unroll
      for (int nf = 0; nf < 4; nf++)
        op[nf * 16] = acc[nf][rr];
    }
  }
}

// ---------------- K5: aggregation ∥ gemm2 source-half (disjoint data) ----------------
__global__ __launch_bounds__(512, 4) void k_agg2s(
    const int* __restrict__ off, const int* __restrict__ deg,
    const int* __restrict__ csr, const float* __restrict__ dinv,
    u16* __restrict__ h1, int n_s, int n_t,
    const u16* __restrict__ W1t, float* __restrict__ out, int nbAgg)
{
  __shared__ u16 Bs[64 * 128];
  if ((int)blockIdx.x < nbAgg){
    int w = blockIdx.x * 8 + (threadIdx.x >> 6);
    aggf_body(off, deg, csr, dinv, h1, n_s, n_t, w, threadIdx.x & 63);
  } else {
    // source rows only: aggf writes target rows; no overlap -> race-free
    gemm2_body(h1, W1t, (int)blockIdx.x - nbAgg, 0, n_s, n_s, out, Bs);
  }
}

// ---------------- K6: gemm2 target-half ----------------
__global__ __launch_bounds__(512, 4) void k_g2t(
    const u16* __restrict__ h1, const u16* __restrict__ W1t,
    int M, int n_s, float* __restrict__ out)
{
  __shared__ u16 Bs[64 * 128];
  gemm2_body(h1, W1t, (int)blockIdx.x, n_s, M, n_s, out, Bs);
}

static inline size_t alup(size_t x){ return (x + 255) & ~(size_t)255; }

extern "C" void kernel_launch(void* const* d_in, const int* in_sizes, int n_in,
                              void* d_out, int out_size, void* d_ws, size_t ws_size,
                              hipStream_t stream)
{
  const int*   ei = (const int*)d_in[0];
  const float* xs = (const float*)d_in[1];
  const float* xt = (const float*)d_in[2];
  const float* W0 = (const float*)d_in[3];
  const float* W1 = (const float*)d_in[4];
  const int E   = in_sizes[0] / 2;
  const int n_s = in_sizes[1] / D_IN;
  const int n_t = in_sizes[2] / D_IN;
  const int M   = n_s + n_t;
  const int* src = ei;       // edge_index row 0
  const int* dst = ei + E;   // edge_index row 1 (0-based target index)

  // workspace layout (~29 MB)
  char* p = (char*)d_ws;
  int*   deg    = (int*)p;    p += alup((size_t)n_t * 4);
  int*   off    = (int*)p;    p += alup((size_t)n_t * 4);
  int*   cursor = (int*)p;    p += alup((size_t)n_t * 4);
  float* dinv   = (float*)p;  p += alup((size_t)n_t * 4);
  int*   csr    = (int*)p;    p += alup((size_t)E * 4);
  u16*   W0t    = (u16*)p;    p += alup((size_t)D_H * D_IN * 2);
  u16*   W1t    = (u16*)p;    p += alup((size_t)D_OUT * D_H * 2);
  u16*   h1     = (u16*)p;    p += alup((size_t)M * D_H * 2);

  const int nb_t   = (n_t + 255) / 256;
  const int nbG1   = (M + 127) / 128;
  const int nbAgg  = (n_t + 7) / 8;
  const int nbG2s  = (n_s + 127) / 128;
  const int nbG2t  = (n_t + 127) / 128;

  const int wprep_n = 128*256 + 64*128 + n_t;
  // K1: weights + deg zero
  k_wprep <<<(wprep_n + 255) / 256, 256, 0, stream>>>(W0, W1, W0t, W1t, deg, n_t);
  // K2: h1 = X @ W0 (all rows, bf16) with deg-count fused
  k_g1deg <<<nbG1, 512, 0, stream>>>(xs, xt, W0t, M, n_s, dst, E, deg, h1);
  // K3: offsets/cursor/dinv (direct deg-sum, no bsum pass)
  k_off   <<<nb_t, 256, 0, stream>>>(deg, n_t, off, cursor, dinv);
  // K4: CSR fill
  k_fill  <<<(E + 255) / 256, 256, 0, stream>>>(src, dst, E, cursor, csr);
  // K5: fused agg (target rows <- u_t) ∥ layer-2 source-half
  k_agg2s <<<nbAgg + nbG2s, 512, 0, stream>>>(off, deg, csr, dinv, h1, n_s, n_t,
                                              W1t, (float*)d_out, nbAgg);
  // K6: layer-2 target-half
  k_g2t   <<<nbG2t, 512, 0, stream>>>(h1, W1t, M, n_s, (float*)d_out);
}

// Round 7
// 259.855 us; speedup vs baseline: 1.0396x; 1.0396x over previous
//
#include <hip/hip_runtime.h>
#include <cstdint>
#include <cstddef>

typedef unsigned short u16;
typedef unsigned int   u32;
typedef __attribute__((ext_vector_type(8))) short bf16x8;
typedef __attribute__((ext_vector_type(4))) float f32x4;

#define D_IN  256
#define D_H   128
#define D_OUT 64

__device__ __forceinline__ float bf2f(u16 u){
  union { u32 i; float f; } v; v.i = ((u32)u) << 16; return v.f;
}
__device__ __forceinline__ u16 f2bf(float f){
  union { float f; u32 i; } v; v.f = f;
  u32 r = (v.i + 0x7fffu + ((v.i >> 16) & 1u)) >> 16;
  return (u16)r;
}

// ---------------- weight prep + deg zero (fused) ----------------
__global__ void k_wprep(const float* __restrict__ W0, const float* __restrict__ W1,
                        u16* __restrict__ W0t, u16* __restrict__ W1t,
                        int* __restrict__ deg, int n_t){
  int i = blockIdx.x * 256 + threadIdx.x;
  if (i < 128 * 256){
    int n = i >> 8, k = i & 255;
    W0t[i] = f2bf(W0[(size_t)k * 128 + n]);
  } else if (i < 128 * 256 + 64 * 128){
    int j = i - 128 * 256;
    int n = j >> 7, k = j & 127;
    W1t[j] = f2bf(W1[(size_t)k * 64 + n]);
  } else if (i - (128 * 256 + 64 * 128) < n_t){
    deg[i - (128 * 256 + 64 * 128)] = 0;
  }
}

// ---------------- offsets: direct deg-sum ----------------
__global__ __launch_bounds__(256) void k_off(const int* __restrict__ deg, int N,
                                             int* __restrict__ off, int* __restrict__ cursor,
                                             float* __restrict__ dinv){
  __shared__ int s[256];
  __shared__ int sbase[256];
  const int tid = threadIdx.x;
  const int bid = blockIdx.x;
  const int i   = bid * 256 + tid;
  int acc = 0;
  const int lim = bid * 256;
  for (int j = tid; j < lim; j += 256) acc += deg[j];
  sbase[tid] = acc;
  int v = (i < N) ? deg[i] : 0;
  s[tid] = v;
  __syncthreads();
  for (int o = 128; o > 0; o >>= 1){
    if (tid < o) sbase[tid] += sbase[tid + o];
    __syncthreads();
  }
  for (int o = 1; o < 256; o <<= 1){
    int tv = (tid >= o) ? s[tid - o] : 0;
    __syncthreads();
    s[tid] += tv;
    __syncthreads();
  }
  if (i < N){
    int excl = s[tid] - v + sbase[0];
    off[i] = excl;
    cursor[i] = excl;
    dinv[i] = rsqrtf((float)v + 1.0f);
  }
}

__global__ void k_fill(const int* __restrict__ src, const int* __restrict__ dst,
                       int E, int* __restrict__ cursor, int* __restrict__ csr){
  int e = blockIdx.x * 256 + threadIdx.x;
  if (e < E){
    int d = dst[e];
    int p = atomicAdd(&cursor[d], 1);
    csr[p] = src[e];
  }
}

// ---------------- K2: deg blocks ∥ GEMM1 blocks (block-range split) ----------------
// gemm1: persistent-B LDS, depth-2 A stream, NEW coalesced LDS-bounce epilogue
// (the 32 scalar u16 col-stride-16 stores were ~2048 cy/wave of store-pipe
// serialization — about half the kernel).
__global__ __launch_bounds__(512, 4) void k_g1(
    const float* __restrict__ Xs, const float* __restrict__ Xt,
    const u16* __restrict__ W0t, int M, int n_s,
    const int* __restrict__ dst, int E, int* __restrict__ deg, int nbDeg,
    u16* __restrict__ out)
{
  __shared__ u16 Bs[128 * 256];   // 64 KB; B cell (n,kbyte) at n*512 + (kbyte ^ ((n&15)<<4))
  const int t = threadIdx.x;

  if ((int)blockIdx.x < nbDeg){
    // dedicated deg-count blocks: pure atomics, no interference with gemm waves
    const int stride = nbDeg * 512;
    for (int e = blockIdx.x * 512 + t; e < E; e += stride)
      atomicAdd(&deg[dst[e]], 1);
    return;
  }

  const int wave = t >> 6, lane = t & 63;
  const int lm   = lane & 15, quad = lane >> 4;
  const int gw   = ((int)blockIdx.x - nbDeg) * 8 + wave;   // global gemm wave id
  const int row  = gw * 16 + lm;

  int cr = (row < M) ? row : 0;
  const float* pa = ((cr < n_s) ? (Xs + (size_t)cr * D_IN)
                                : (Xt + (size_t)(cr - n_s) * D_IN)) + quad * 8;

  float4 a[8][2];
  a[0][0] = *(const float4*)(pa +  0); a[0][1] = *(const float4*)(pa +  4);
  a[1][0] = *(const float4*)(pa + 32); a[1][1] = *(const float4*)(pa + 36);

  // stage B once: thread t -> n = t>>2 (0..127), 128 B chunk c = t&3
  {
    const int n = t >> 2;
    const int c = t & 3;
    const u16* wsrc = W0t + (size_t)n * 256 + c * 64;
    char* brow = (char*)Bs + n * 512;
    const int sw = (n & 15) << 4;
    #pragma unroll
    for (int j = 0; j < 8; j++){
      int off = (c * 128 + j * 16) ^ sw;
      *(int4*)(brow + off) = *(const int4*)(wsrc + j * 8);
    }
  }

  #pragma unroll
  for (int s = 2; s < 8; s++){
    a[s][0] = *(const float4*)(pa + s * 32);
    a[s][1] = *(const float4*)(pa + s * 32 + 4);
  }
  __builtin_amdgcn_sched_barrier(0);

  f32x4 acc[8];
  const f32x4 z = {0.f, 0.f, 0.f, 0.f};
  #pragma unroll
  for (int nf = 0; nf < 8; nf++) acc[nf] = z;

  __syncthreads();

  const char* bb = (const char*)Bs + lm * 512;
  const int lmx = lm << 4;

  #pragma unroll
  for (int kk = 0; kk < 8; kk++){
    bf16x8 af;
    {
      const float* fa = (const float*)&a[kk][0];
      u16 tmp[8];
      #pragma unroll
      for (int q = 0; q < 8; q++) tmp[q] = f2bf(fa[q]);
      af = *(const bf16x8*)tmp;
    }
    const int koff = (kk * 64 + quad * 16) ^ lmx;
    #pragma unroll
    for (int nf = 0; nf < 8; nf++){
      bf16x8 bf = *(const bf16x8*)(bb + nf * 8192 + koff);
      acc[nf] = __builtin_amdgcn_mfma_f32_16x16x32_bf16(af, bf, acc[nf], 0, 0, 0);
    }
  }

  // ---- coalesced epilogue: bounce through Bs (reused), then 1 KB row stores ----
  __syncthreads();                        // all waves done reading B
  u16* wreg = Bs + wave * 2048;           // [16 rows][128 u16], swizzled
  #pragma unroll
  for (int nf = 0; nf < 8; nf++){
    #pragma unroll
    for (int rr = 0; rr < 4; rr++){
      int rl = quad * 4 + rr;
      int c  = nf * 16 + lm;
      wreg[rl * 128 + (c ^ (quad << 5))] = f2bf(acc[nf][rr]);
    }
  }
  {
    const int g = lane >> 4, l = lane & 15;
    const int wrow0 = gw * 16;
    #pragma unroll
    for (int i = 0; i < 4; i++){
      int rl = i * 4 + g;
      int m  = wrow0 + rl;
      bf16x8 v = *(const bf16x8*)&wreg[rl * 128 + ((l ^ (i << 2)) << 3)];
      if (m < M) *(bf16x8*)(out + (size_t)m * D_H + l * 8) = v;
    }
  }
}

// ---------------- aggregation body (one wave per dst node) ----------------
__device__ __forceinline__ void aggf_body(
    const int* __restrict__ off, const int* __restrict__ deg,
    const int* __restrict__ csr, const float* __restrict__ dinv,
    u16* __restrict__ h1, int n_s, int n_t, int w, int lane)
{
  if (w >= n_t) return;
  const int g = lane >> 4;
  const int c = lane & 15;
  int start = off[w];
  int n     = deg[w];

  float r[8], p[8];
  #pragma unroll
  for (int q = 0; q < 8; q++){ r[q] = 0.f; p[q] = 0.f; }

  int i = 0;
  for (; i + 8 <= n; i += 8){
    int sa = csr[start + i + g];
    int sb = csr[start + i + 4 + g];
    int4 da = *(const int4*)(h1 + (size_t)sa * D_H + c * 8);
    int4 db = *(const int4*)(h1 + (size_t)sb * D_H + c * 8);
    const u16* ha = (const u16*)&da;
    const u16* hb = (const u16*)&db;
    #pragma unroll
    for (int q = 0; q < 8; q++){
      float va = bf2f(ha[q]), vb = bf2f(hb[q]);
      r[q] += va + vb;
      p[q] += fmaxf(va, 0.f) + fmaxf(vb, 0.f);
    }
  }
  for (; i < n; i += 4){
    if (i + g < n){
      int sa = csr[start + i + g];
      int4 da = *(const int4*)(h1 + (size_t)sa * D_H + c * 8);
      const u16* ha = (const u16*)&da;
      #pragma unroll
      for (int q = 0; q < 8; q++){
        float va = bf2f(ha[q]);
        r[q] += va;
        p[q] += fmaxf(va, 0.f);
      }
    }
  }

  #pragma unroll
  for (int q = 0; q < 8; q++){
    r[q] += __shfl_xor(r[q], 16, 64);
    r[q] += __shfl_xor(r[q], 32, 64);
    p[q] += __shfl_xor(p[q], 16, 64);
    p[q] += __shfl_xor(p[q], 32, 64);
  }

  if (g == 0){
    float di  = dinv[w];
    float di2 = di * di;
    u16* selfp = h1 + (size_t)(n_s + w) * D_H + c * 8;
    int4 hs = *(const int4*)selfp;
    const u16* hh = (const u16*)&hs;
    u16 ob[8];
    #pragma unroll
    for (int q = 0; q < 8; q++){
      float zq = fmaxf(di * r[q] + di2 * bf2f(hh[q]), 0.f);
      float uq = di * p[q] + di2 * zq;
      ob[q] = f2bf(uq);
    }
    *(int4*)selfp = *(int4*)ob;
  }
}

// ---------------- gemm2 body (B=16 KB LDS, coalesced bounce epilogue) ----------------
__device__ __forceinline__ bf16x8 relu_bf(int4 v, bool relu){
  const u16* s = (const u16*)&v;
  u16 tmp[8];
  #pragma unroll
  for (int q = 0; q < 8; q++){
    u16 x = s[q];
    tmp[q] = (relu && (x & 0x8000u)) ? (u16)0 : x;
  }
  return *(const bf16x8*)tmp;
}

__device__ __forceinline__ void gemm2_body(
    const u16* __restrict__ h1, const u16* __restrict__ W1t,
    int gb, int base, int rowLim, int n_s, float* __restrict__ out,
    u16* Bs, float* Cb)
{
  const int t    = threadIdx.x;
  const int wave = t >> 6, lane = t & 63;
  const int lm   = lane & 15, quad = lane >> 4;
  const int gw   = gb * 8 + wave;
  const int row  = base + gw * 16 + lm;

  int cr = (row < rowLim) ? row : base;
  const bool relu = (cr < n_s);
  const u16* pa = h1 + (size_t)cr * D_H + quad * 8;

  int4 a[4];
  a[0] = *(const int4*)(pa);
  a[1] = *(const int4*)(pa + 32);

  // stage B once: thread t -> n = t>>3 (0..63), 32 B chunk c = t&7
  {
    const int n = t >> 3;
    const int c = t & 7;
    const u16* wsrc = W1t + (size_t)n * 128 + c * 16;
    char* brow = (char*)Bs + n * 256;
    const int sw = (n & 15) << 4;
    #pragma unroll
    for (int j = 0; j < 2; j++){
      int off = (c * 32 + j * 16) ^ sw;
      *(int4*)(brow + off) = *(const int4*)(wsrc + j * 8);
    }
  }
  a[2] = *(const int4*)(pa + 64);
  a[3] = *(const int4*)(pa + 96);
  __builtin_amdgcn_sched_barrier(0);

  f32x4 acc[4];
  const f32x4 z = {0.f, 0.f, 0.f, 0.f};
  #pragma unroll
  for (int nf = 0; nf < 4; nf++) acc[nf] = z;

  __syncthreads();

  const char* bb = (const char*)Bs + lm * 256;
  const int lmx = lm << 4;

  #pragma unroll
  for (int kk = 0; kk < 4; kk++){
    bf16x8 af = relu_bf(a[kk], relu);
    const int koff = (kk * 64 + quad * 16) ^ lmx;
    #pragma unroll
    for (int nf = 0; nf < 4; nf++){
      bf16x8 bf = *(const bf16x8*)(bb + nf * 4096 + koff);
      acc[nf] = __builtin_amdgcn_mfma_f32_16x16x32_bf16(af, bf, acc[nf], 0, 0, 0);
    }
  }

  // ---- coalesced epilogue: bounce through Cb (own region per wave) ----
  float* wreg = Cb + wave * 1024;   // [16 rows][64 f32], swizzled
  #pragma unroll
  for (int nf = 0; nf < 4; nf++){
    #pragma unroll
    for (int rr = 0; rr < 4; rr++){
      int rl = quad * 4 + rr;
      int c  = nf * 16 + lm;
      wreg[rl * 64 + (c ^ (quad << 4))] = acc[nf][rr];
    }
  }
  {
    const int g = lane >> 4, l = lane & 15;
    const int wrow0 = base + gw * 16;
    #pragma unroll
    for (int i = 0; i < 4; i++){
      int rl = i * 4 + g;
      int m  = wrow0 + rl;
      float4 v = *(const float4*)&wreg[rl * 64 + ((l ^ (i << 2)) << 2)];
      if (m < rowLim) *(float4*)(out + (size_t)m * D_OUT + l * 4) = v;
    }
  }
}

// ---------------- K5: aggregation ∥ gemm2 source-half (disjoint data) ----------------
__global__ __launch_bounds__(512, 4) void k_agg2s(
    const int* __restrict__ off, const int* __restrict__ deg,
    const int* __restrict__ csr, const float* __restrict__ dinv,
    u16* __restrict__ h1, int n_s, int n_t,
    const u16* __restrict__ W1t, float* __restrict__ out, int nbAgg)
{
  __shared__ u16  Bs[64 * 128];
  __shared__ float Cb[8 * 1024];
  if ((int)blockIdx.x < nbAgg){
    int w = blockIdx.x * 8 + (threadIdx.x >> 6);
    aggf_body(off, deg, csr, dinv, h1, n_s, n_t, w, threadIdx.x & 63);
  } else {
    // source rows only: aggf writes target rows; no overlap -> race-free
    gemm2_body(h1, W1t, (int)blockIdx.x - nbAgg, 0, n_s, n_s, out, Bs, Cb);
  }
}

// ---------------- K6: gemm2 target-half ----------------
__global__ __launch_bounds__(512, 4) void k_g2t(
    const u16* __restrict__ h1, const u16* __restrict__ W1t,
    int M, int n_s, float* __restrict__ out)
{
  __shared__ u16  Bs[64 * 128];
  __shared__ float Cb[8 * 1024];
  gemm2_body(h1, W1t, (int)blockIdx.x, n_s, M, n_s, out, Bs, Cb);
}

static inline size_t alup(size_t x){ return (x + 255) & ~(size_t)255; }

extern "C" void kernel_launch(void* const* d_in, const int* in_sizes, int n_in,
                              void* d_out, int out_size, void* d_ws, size_t ws_size,
                              hipStream_t stream)
{
  const int*   ei = (const int*)d_in[0];
  const float* xs = (const float*)d_in[1];
  const float* xt = (const float*)d_in[2];
  const float* W0 = (const float*)d_in[3];
  const float* W1 = (const float*)d_in[4];
  const int E   = in_sizes[0] / 2;
  const int n_s = in_sizes[1] / D_IN;
  const int n_t = in_sizes[2] / D_IN;
  const int M   = n_s + n_t;
  const int* src = ei;       // edge_index row 0
  const int* dst = ei + E;   // edge_index row 1 (0-based target index)

  // workspace layout (~29 MB)
  char* p = (char*)d_ws;
  int*   deg    = (int*)p;    p += alup((size_t)n_t * 4);
  int*   off    = (int*)p;    p += alup((size_t)n_t * 4);
  int*   cursor = (int*)p;    p += alup((size_t)n_t * 4);
  float* dinv   = (float*)p;  p += alup((size_t)n_t * 4);
  int*   csr    = (int*)p;    p += alup((size_t)E * 4);
  u16*   W0t    = (u16*)p;    p += alup((size_t)D_H * D_IN * 2);
  u16*   W1t    = (u16*)p;    p += alup((size_t)D_OUT * D_H * 2);
  u16*   h1     = (u16*)p;    p += alup((size_t)M * D_H * 2);

  const int nb_t   = (n_t + 255) / 256;
  const int nbDeg  = 64;
  const int nbG1   = (M + 127) / 128;
  const int nbAgg  = (n_t + 7) / 8;
  const int nbG2s  = (n_s + 127) / 128;
  const int nbG2t  = (n_t + 127) / 128;

  const int wprep_n = 128*256 + 64*128 + n_t;
  // K1: weights + deg zero
  k_wprep <<<(wprep_n + 255) / 256, 256, 0, stream>>>(W0, W1, W0t, W1t, deg, n_t);
  // K2: deg blocks ∥ gemm1 blocks
  k_g1    <<<nbDeg + nbG1, 512, 0, stream>>>(xs, xt, W0t, M, n_s, dst, E, deg, nbDeg, h1);
  // K3: offsets/cursor/dinv
  k_off   <<<nb_t, 256, 0, stream>>>(deg, n_t, off, cursor, dinv);
  // K4: CSR fill
  k_fill  <<<(E + 255) / 256, 256, 0, stream>>>(src, dst, E, cursor, csr);
  // K5: fused agg (target rows <- u_t) ∥ layer-2 source-half
  k_agg2s <<<nbAgg + nbG2s, 512, 0, stream>>>(off, deg, csr, dinv, h1, n_s, n_t,
                                              W1t, (float*)d_out, nbAgg);
  // K6: layer-2 target-half
  k_g2t   <<<nbG2t, 512, 0, stream>>>(h1, W1t, M, n_s, (float*)d_out);
}